// Round 5
// baseline (847.573 us; speedup 1.0000x reference)
//
#include <hip/hip_runtime.h>

#define NSUP 4096
#define NTOT 8192
#define DIN  512
#define DEMB 256
#define NCLS 64

typedef __attribute__((ext_vector_type(8))) short bf16x8;
typedef __attribute__((ext_vector_type(4))) float f32x4;
typedef __attribute__((ext_vector_type(4))) unsigned int u32x4;

typedef const __attribute__((address_space(1))) unsigned int* gas1_t;
typedef __attribute__((address_space(3))) unsigned int* las3_t;
__device__ inline void glds16(const void* g, void* l) {
  __builtin_amdgcn_global_load_lds((gas1_t)g, (las3_t)l, 16, 0, 0);
}

__device__ inline unsigned short f2bf(float x) {
  unsigned int u = __builtin_bit_cast(unsigned int, x);
  u += 0x7FFFu + ((u >> 16) & 1u);   // RNE
  return (unsigned short)(u >> 16);
}
__device__ inline float bf2f(unsigned short h) {
  unsigned int u = ((unsigned int)h) << 16;
  return __builtin_bit_cast(float, u);
}

// fragment-major offset for a [NTOT][DEMB] bf16 matrix (A- and B-side identical):
// [row>>4][col>>5][(row&15)+16*((col>>3)&3)][col&7]
// Lt fragment-major (K=node i, N=class c): [i>>5][c>>4][(c&15)+16*((i>>3)&3)][i&7]
__device__ inline size_t lfrag(int i, int c) {
  return (((size_t)(i >> 5) * (NCLS / 16) + (c >> 4)) * 64 +
          (c & 15) + 16 * ((i >> 3) & 3)) * 8 + (i & 7);
}

// ---------- 1a) split X (fp32 -> bf16 hi/lo) into fragment-major [8192][512] ----------
__global__ __launch_bounds__(256) void splitX(
    const float* __restrict__ support, const float* __restrict__ query,
    unsigned short* __restrict__ XhF, unsigned short* __restrict__ XlF) {
  int w = threadIdx.x >> 6, lane = threadIdx.x & 63;
  int row = blockIdx.x * 4 + w;
  const float* X = (row < NSUP) ? (support + (size_t)row * DIN)
                                : (query + (size_t)(row - NSUP) * DIN);
  const float4* p = (const float4*)(X + lane * 8);
  float4 a = p[0], b = p[1];
  float v[8] = {a.x, a.y, a.z, a.w, b.x, b.y, b.z, b.w};
  bf16x8 hv, lv;
  #pragma unroll
  for (int j = 0; j < 8; j++) {
    unsigned short h = f2bf(v[j]);
    hv[j] = (short)h;
    lv[j] = (short)f2bf(v[j] - bf2f(h));
  }
  size_t off = (((size_t)(row >> 4) * (DIN / 32) + (lane >> 2)) * 64 +
                (row & 15) + 16 * (lane & 3)) * 8;
  *reinterpret_cast<bf16x8*>(XhF + off) = hv;
  *reinterpret_cast<bf16x8*>(XlF + off) = lv;
}

// ---------- 1b) split W [512][256] into B-side fragment-major ----------
__global__ __launch_bounds__(256) void splitW(
    const float* __restrict__ W, unsigned short* __restrict__ WhF,
    unsigned short* __restrict__ WlF) {
  int idx = blockIdx.x * 256 + threadIdx.x;
  int n = idx & 255, kb8 = idx >> 8;       // kb8 = k-octet 0..63
  bf16x8 hv, lv;
  #pragma unroll
  for (int j = 0; j < 8; j++) {
    float v = W[(size_t)(kb8 * 8 + j) * DEMB + n];
    unsigned short h = f2bf(v);
    hv[j] = (short)h;
    lv[j] = (short)f2bf(v - bf2f(h));
  }
  size_t off = (((size_t)(n >> 4) * (DIN / 32) + (kb8 >> 2)) * 64 +
                (n & 15) + 16 * (kb8 & 3)) * 8;
  *reinterpret_cast<bf16x8*>(WhF + off) = hv;
  *reinterpret_cast<bf16x8*>(WlF + off) = lv;
}

// ---------- 1c) emb = X @ W via 4-product split-bf16 MFMA -> ehiF/eloF frag-major ----------
__global__ __launch_bounds__(256) void emb_mfma(
    const unsigned short* __restrict__ XhF, const unsigned short* __restrict__ XlF,
    const unsigned short* __restrict__ WhF, const unsigned short* __restrict__ WlF,
    unsigned short* __restrict__ ehiF, unsigned short* __restrict__ eloF) {
  __shared__ float lds[4][16][65];
  int lane = threadIdx.x & 63, w = threadIdx.x >> 6;
  int l15 = lane & 15, lg = lane >> 4;
  int rowblk0 = blockIdx.x * 2;            // 32 rows per block
  f32x4 acc[2][4] = {};
  for (int kb = 0; kb < DIN / 32; kb++) {
    bf16x8 ah[2], al[2], bh[4], bl[4];
    #pragma unroll
    for (int fm = 0; fm < 2; fm++) {
      size_t o = (((size_t)(rowblk0 + fm) * (DIN / 32) + kb) * 64 + lane) * 8;
      ah[fm] = *reinterpret_cast<const bf16x8*>(XhF + o);
      al[fm] = *reinterpret_cast<const bf16x8*>(XlF + o);
    }
    #pragma unroll
    for (int fn = 0; fn < 4; fn++) {
      size_t o = (((size_t)(w * 4 + fn) * (DIN / 32) + kb) * 64 + lane) * 8;
      bh[fn] = *reinterpret_cast<const bf16x8*>(WhF + o);
      bl[fn] = *reinterpret_cast<const bf16x8*>(WlF + o);
    }
    #pragma unroll
    for (int fm = 0; fm < 2; fm++)
      #pragma unroll
      for (int fn = 0; fn < 4; fn++) {
        acc[fm][fn] = __builtin_amdgcn_mfma_f32_16x16x32_bf16(ah[fm], bh[fn], acc[fm][fn], 0, 0, 0);
        acc[fm][fn] = __builtin_amdgcn_mfma_f32_16x16x32_bf16(ah[fm], bl[fn], acc[fm][fn], 0, 0, 0);
        acc[fm][fn] = __builtin_amdgcn_mfma_f32_16x16x32_bf16(al[fm], bh[fn], acc[fm][fn], 0, 0, 0);
        acc[fm][fn] = __builtin_amdgcn_mfma_f32_16x16x32_bf16(al[fm], bl[fn], acc[fm][fn], 0, 0, 0);
      }
  }
  // C/D (col=l15,row=lg*4+r) -> fragment-major via LDS permute
  for (int fm = 0; fm < 2; fm++) {
    #pragma unroll
    for (int fn = 0; fn < 4; fn++)
      #pragma unroll
      for (int r = 0; r < 4; r++)
        lds[w][lg * 4 + r][fn * 16 + l15] = acc[fm][fn][r];
    __syncthreads();
    #pragma unroll
    for (int cb = 0; cb < 2; cb++) {
      const float* src = &lds[w][l15][cb * 32 + lg * 8];
      bf16x8 hv, lv;
      #pragma unroll
      for (int j = 0; j < 8; j++) {
        float v = src[j];
        unsigned short h = f2bf(v);
        hv[j] = (short)h;
        lv[j] = (short)f2bf(v - bf2f(h));
      }
      size_t off = (((size_t)(rowblk0 + fm) * (DEMB / 32) + w * 2 + cb) * 64 + lane) * 8;
      *reinterpret_cast<bf16x8*>(ehiF + off) = hv;
      *reinterpret_cast<bf16x8*>(eloF + off) = lv;
    }
    __syncthreads();
  }
}

// ---------- 2) similarity (split-bf16, LDS-staged) -> Apk (both triangles, prop-ready) ----------
__global__ __launch_bounds__(256) void sim_kernel(
    const unsigned short* __restrict__ ehiF, const unsigned short* __restrict__ eloF,
    unsigned int* __restrict__ Apk) {
  int bx = blockIdx.x, by = blockIdx.y;
  if (bx < by) return;                       // A symmetric: this block writes both triangles
  __shared__ unsigned short stg[32][512];    // 32 KB: tiles 0-7 A-hi, 8-15 A-lo, 16-23 B-hi, 24-31 B-lo
  __shared__ unsigned short LTn[128][8];     // normal bit-rows (row-local, ushort per 16 cols)
  __shared__ unsigned short LTt[128][8];     // transposed
  int lane = threadIdx.x & 63;
  int w = threadIdx.x >> 6, wm = w >> 1, wn = w & 1;
  int l15 = lane & 15, lg = lane >> 4;

  f32x4 acc[4][4] = {};
  for (int kb = 0; kb < DEMB / 32; kb++) {
    #pragma unroll
    for (int i = 0; i < 8; i++) {
      int t = w * 8 + i;
      const unsigned short* src;
      if (t < 8)       src = ehiF + ((size_t)(by * 8 + t) * 8 + kb) * 512;
      else if (t < 16) src = eloF + ((size_t)(by * 8 + t - 8) * 8 + kb) * 512;
      else if (t < 24) src = ehiF + ((size_t)(bx * 8 + t - 16) * 8 + kb) * 512;
      else             src = eloF + ((size_t)(bx * 8 + t - 24) * 8 + kb) * 512;
      glds16(src + lane * 8, &stg[t][lane * 8]);
    }
    __syncthreads();
    bf16x8 bh[4], bl[4];
    #pragma unroll
    for (int fn = 0; fn < 4; fn++) {
      bh[fn] = *reinterpret_cast<const bf16x8*>(&stg[16 + wn * 4 + fn][lane * 8]);
      bl[fn] = *reinterpret_cast<const bf16x8*>(&stg[24 + wn * 4 + fn][lane * 8]);
    }
    #pragma unroll
    for (int fm = 0; fm < 4; fm++) {
      bf16x8 ah = *reinterpret_cast<const bf16x8*>(&stg[wm * 4 + fm][lane * 8]);
      bf16x8 al = *reinterpret_cast<const bf16x8*>(&stg[8 + wm * 4 + fm][lane * 8]);
      #pragma unroll
      for (int fn = 0; fn < 4; fn++) {
        acc[fm][fn] = __builtin_amdgcn_mfma_f32_16x16x32_bf16(ah, bh[fn], acc[fm][fn], 0, 0, 0);
        acc[fm][fn] = __builtin_amdgcn_mfma_f32_16x16x32_bf16(ah, bl[fn], acc[fm][fn], 0, 0, 0);
        acc[fm][fn] = __builtin_amdgcn_mfma_f32_16x16x32_bf16(al, bh[fn], acc[fm][fn], 0, 0, 0);
      }
    }
    __syncthreads();
  }
  // threshold + ballot; build normal and transposed bit-rows in LDS
  #pragma unroll
  for (int fm = 0; fm < 4; fm++)
    #pragma unroll
    for (int fn = 0; fn < 4; fn++) {
      unsigned long long bal[4];
      #pragma unroll
      for (int r = 0; r < 4; r++) {
        bal[r] = __ballot(acc[fm][fn][r] > 0.5f);
        if (l15 == 0)
          LTn[wm * 64 + fm * 16 + lg * 4 + r][wn * 4 + fn] =
              (unsigned short)(bal[r] >> (lg * 16));
      }
      unsigned int tv = 0;
      #pragma unroll
      for (int p = 0; p < 16; p++) {
        unsigned int half = (unsigned int)(bal[p & 3] >> ((p >> 2) * 16));
        tv |= ((half >> l15) & 1u) << p;
      }
      if (lg == 0) LTt[wn * 64 + fn * 16 + l15][wm * 4 + fm] = (unsigned short)tv;
    }
  __syncthreads();
  // assemble Apk dwords: dword(rowblk,S4,lane={l15=row&15,lg}) bytes t = bits k=S4*128+t*32+lg*8
  #pragma unroll
  for (int pass = 0; pass < 2; pass++) {
    int idx = pass * 256 + threadIdx.x;      // 0..511
    int rb4 = idx >> 6, ln = idx & 63;
    int lr = rb4 * 16 + (ln & 15), Lg = ln >> 4;
    unsigned int d = 0, d2 = 0;
    #pragma unroll
    for (int t = 0; t < 4; t++) {
      int bix = t * 4 + Lg;
      unsigned int u = LTn[lr][bix >> 1];
      d |= ((u >> ((bix & 1) * 8)) & 0xffu) << (t * 8);
      unsigned int u2 = LTt[lr][bix >> 1];
      d2 |= ((u2 >> ((bix & 1) * 8)) & 0xffu) << (t * 8);
    }
    Apk[((size_t)(by * 8 + rb4) * 64 + bx) * 64 + ln] = d;
    Apk[((size_t)(bx * 8 + rb4) * 64 + by) * 64 + ln] = d2;
  }
}

// ---------- 3) rdeg = 1/popcount, straight from Apk (coalesced) ----------
__global__ __launch_bounds__(256) void degree_kernel(
    const unsigned int* __restrict__ Apk, float* __restrict__ rdeg) {
  __shared__ int dg[4][16];
  int rowblk = blockIdx.x;
  int w = threadIdx.x >> 6, lane = threadIdx.x & 63;
  const unsigned int* base = Apk + (size_t)rowblk * 4096;
  int cnt = 0;
  #pragma unroll
  for (int s = 0; s < 16; s++) cnt += __popc(base[(w * 16 + s) * 64 + lane]);
  cnt += __shfl_xor(cnt, 16);
  cnt += __shfl_xor(cnt, 32);
  if (lane < 16) dg[w][lane] = cnt;
  __syncthreads();
  if (threadIdx.x < 16) {
    int c = dg[0][threadIdx.x] + dg[1][threadIdx.x] + dg[2][threadIdx.x] + dg[3][threadIdx.x];
    rdeg[rowblk * 16 + threadIdx.x] = (c == 0) ? 1.f : 1.f / (float)c;
  }
}

// ---------- 4) label init: support one-hot, query zero ----------
__global__ __launch_bounds__(256) void init_labels(
    const int* __restrict__ slab, float* __restrict__ labels,
    unsigned short* __restrict__ LtF) {
  int idx = blockIdx.x * 256 + threadIdx.x;
  int i = idx >> 6, c = idx & 63;
  float v = 0.f;
  if (i < NSUP && slab[i] == c) v = 1.f;
  labels[idx] = v;
  LtF[lfrag(i, c)] = f2bf(v);
}

// ---------- 5) fused prop: labels' = 0.5*labels + 0.5*(A@L)/deg ----------
// 256 blocks x 512 thr (8 waves = 2 wr x 4 wk): wave = 16 rows x 64 cols x K-chunk 2048
__global__ __launch_bounds__(512) void prop_kernel(
    const unsigned int* __restrict__ Apk, const unsigned short* __restrict__ LtinF,
    const float* __restrict__ rdeg, float* __restrict__ labels,
    unsigned short* __restrict__ LtoutF, float* __restrict__ outq, int last) {
  __shared__ float red[4][32][65];
  int lane = threadIdx.x & 63;
  int wv = threadIdx.x >> 6;
  int wr = wv >> 2, wk = wv & 3;
  int l15 = lane & 15, lg = lane >> 4;
  int rowblk = blockIdx.x * 2 + wr;
  const unsigned int* ap = Apk + ((size_t)rowblk * 64 + wk * 16) * 64 + lane;
  f32x4 acc[4] = {};
  for (int s4 = 0; s4 < 16; s4++) {
    unsigned int d = ap[s4 * 64];
    #pragma unroll
    for (int t = 0; t < 4; t++) {
      unsigned int bb = (d >> (8 * t)) & 0xffu;
      u32x4 uu;
      uu.x = ((bb & 1u)   ? 0x3F80u : 0u) | ((bb & 2u)   ? 0x3F800000u : 0u);
      uu.y = ((bb & 4u)   ? 0x3F80u : 0u) | ((bb & 8u)   ? 0x3F800000u : 0u);
      uu.z = ((bb & 16u)  ? 0x3F80u : 0u) | ((bb & 32u)  ? 0x3F800000u : 0u);
      uu.w = ((bb & 64u)  ? 0x3F80u : 0u) | ((bb & 128u) ? 0x3F800000u : 0u);
      bf16x8 a = __builtin_bit_cast(bf16x8, uu);
      int kstep = (wk * 16 + s4) * 4 + t;
      #pragma unroll
      for (int fn = 0; fn < 4; fn++) {
        bf16x8 b = *reinterpret_cast<const bf16x8*>(
            LtinF + (((size_t)kstep * 4 + fn) * 64 + lane) * 8);
        acc[fn] = __builtin_amdgcn_mfma_f32_16x16x32_bf16(a, b, acc[fn], 0, 0, 0);
      }
    }
  }
  #pragma unroll
  for (int fn = 0; fn < 4; fn++)
    #pragma unroll
    for (int r = 0; r < 4; r++)
      red[wk][wr * 16 + lg * 4 + r][fn * 16 + l15] = acc[fn][r];
  __syncthreads();
  for (int e = threadIdx.x; e < 32 * 64; e += 512) {
    int il = e >> 6, c = e & 63;
    float s = red[0][il][c] + red[1][il][c] + red[2][il][c] + red[3][il][c];
    int i = blockIdx.x * 32 + il;
    size_t idx = (size_t)i * NCLS + c;
    float v = 0.5f * labels[idx] + 0.5f * (s * rdeg[i]);
    labels[idx] = v;
    LtoutF[lfrag(i, c)] = f2bf(v);
    if (last && i >= NSUP) outq[idx - (size_t)NSUP * NCLS] = v;
  }
}

extern "C" void kernel_launch(void* const* d_in, const int* in_sizes, int n_in,
                              void* d_out, int out_size, void* d_ws, size_t ws_size,
                              hipStream_t stream) {
  const float* support = (const float*)d_in[0];
  const float* query   = (const float*)d_in[1];
  const float* W       = (const float*)d_in[2];
  const int*   slab    = (const int*)d_in[3];
  float* out = (float*)d_out;
  char* ws = (char*)d_ws;
  const size_t MB = (size_t)1 << 20;
  // Apk (written by sim, after emb_mfma is done) aliases XhF's region.
  unsigned short* XhF    = (unsigned short*)(ws);            // 8 MB (dead after emb_mfma)
  unsigned int*   Apk    = (unsigned int*)(ws);              // 8 MB (alias)
  unsigned short* XlF    = (unsigned short*)(ws + 8 * MB);   // 8 MB
  unsigned short* ehiF   = (unsigned short*)(ws + 16 * MB);  // 4 MB
  unsigned short* eloF   = (unsigned short*)(ws + 20 * MB);  // 4 MB
  unsigned short* WhF    = (unsigned short*)(ws + 24 * MB);  // 256 KB
  unsigned short* WlF    = (unsigned short*)(ws + 24 * MB + 256 * 1024); // 256 KB
  float*          labels = (float*)(ws + 25 * MB);           // 2 MB fp32 [8192][64]
  unsigned short* Lt0    = (unsigned short*)(ws + 27 * MB);  // 1 MB frag-major
  unsigned short* Lt1    = (unsigned short*)(ws + 28 * MB);  // 1 MB
  float*          rdeg   = (float*)(ws + 29 * MB);           // 32 KB

  splitX<<<NTOT / 4, 256, 0, stream>>>(support, query, XhF, XlF);
  splitW<<<DIN * DEMB / 8 / 256, 256, 0, stream>>>(W, WhF, WlF);
  emb_mfma<<<NTOT / 32, 256, 0, stream>>>(XhF, XlF, WhF, WlF, ehiF, eloF);
  sim_kernel<<<dim3(64, 64), 256, 0, stream>>>(ehiF, eloF, Apk);
  degree_kernel<<<NTOT / 16, 256, 0, stream>>>(Apk, rdeg);
  init_labels<<<NTOT * NCLS / 256, 256, 0, stream>>>(slab, labels, Lt0);
  for (int t = 0; t < 10; t++) {
    unsigned short* Li = (t & 1) ? Lt1 : Lt0;
    unsigned short* Lo = (t & 1) ? Lt0 : Lt1;
    prop_kernel<<<NTOT / 32, 512, 0, stream>>>(Apk, Li, rdeg, labels, Lo, out, (t == 9) ? 1 : 0);
  }
}

// Round 6
// 391.213 us; speedup vs baseline: 2.1665x; 2.1665x over previous
//
#include <hip/hip_runtime.h>

#define NSUP 4096
#define NTOT 8192
#define DIN  512
#define DEMB 256
#define NCLS 64

typedef __attribute__((ext_vector_type(8))) short bf16x8;
typedef __attribute__((ext_vector_type(4))) float f32x4;
typedef __attribute__((ext_vector_type(4))) unsigned int u32x4;

__device__ inline unsigned short f2bf(float x) {
  unsigned int u = __builtin_bit_cast(unsigned int, x);
  u += 0x7FFFu + ((u >> 16) & 1u);   // RNE
  return (unsigned short)(u >> 16);
}
__device__ inline float bf2f(unsigned short h) {
  unsigned int u = ((unsigned int)h) << 16;
  return __builtin_bit_cast(float, u);
}

// fragment-major layouts:
// e[Hi/Lo]F: [row>>4][col>>5][(row&15)+16*((col>>3)&3)][col&7]   (A- and B-side identical)
// LtF:       [i>>5][c>>4][(c&15)+16*((i>>3)&3)][i&7]
__device__ inline size_t lfrag(int i, int c) {
  return (((size_t)(i >> 5) * (NCLS / 16) + (c >> 4)) * 64 +
          (c & 15) + 16 * ((i >> 3) & 3)) * 8 + (i & 7);
}

// ---------- 1a) split X (fp32 -> bf16 hi/lo) into fragment-major [8192][512] ----------
__global__ __launch_bounds__(256) void splitX(
    const float* __restrict__ support, const float* __restrict__ query,
    unsigned short* __restrict__ XhF, unsigned short* __restrict__ XlF) {
  int w = threadIdx.x >> 6, lane = threadIdx.x & 63;
  int row = blockIdx.x * 4 + w;
  const float* X = (row < NSUP) ? (support + (size_t)row * DIN)
                                : (query + (size_t)(row - NSUP) * DIN);
  const float4* p = (const float4*)(X + lane * 8);
  float4 a = p[0], b = p[1];
  float v[8] = {a.x, a.y, a.z, a.w, b.x, b.y, b.z, b.w};
  bf16x8 hv, lv;
  #pragma unroll
  for (int j = 0; j < 8; j++) {
    unsigned short h = f2bf(v[j]);
    hv[j] = (short)h;
    lv[j] = (short)f2bf(v[j] - bf2f(h));
  }
  size_t off = (((size_t)(row >> 4) * (DIN / 32) + (lane >> 2)) * 64 +
                (row & 15) + 16 * (lane & 3)) * 8;
  *reinterpret_cast<bf16x8*>(XhF + off) = hv;
  *reinterpret_cast<bf16x8*>(XlF + off) = lv;
}

// ---------- 1b) split W [512][256] into B-side fragment-major ----------
__global__ __launch_bounds__(256) void splitW(
    const float* __restrict__ W, unsigned short* __restrict__ WhF,
    unsigned short* __restrict__ WlF) {
  int idx = blockIdx.x * 256 + threadIdx.x;
  int n = idx & 255, kb8 = idx >> 8;       // kb8 = k-octet 0..63
  bf16x8 hv, lv;
  #pragma unroll
  for (int j = 0; j < 8; j++) {
    float v = W[(size_t)(kb8 * 8 + j) * DEMB + n];
    unsigned short h = f2bf(v);
    hv[j] = (short)h;
    lv[j] = (short)f2bf(v - bf2f(h));
  }
  size_t off = (((size_t)(n >> 4) * (DIN / 32) + (kb8 >> 2)) * 64 +
                (n & 15) + 16 * (kb8 & 3)) * 8;
  *reinterpret_cast<bf16x8*>(WhF + off) = hv;
  *reinterpret_cast<bf16x8*>(WlF + off) = lv;
}

// ---------- 1c) emb = X @ W via 4-product split-bf16 MFMA -> ehiF/eloF frag-major ----------
__global__ __launch_bounds__(256) void emb_mfma(
    const unsigned short* __restrict__ XhF, const unsigned short* __restrict__ XlF,
    const unsigned short* __restrict__ WhF, const unsigned short* __restrict__ WlF,
    unsigned short* __restrict__ ehiF, unsigned short* __restrict__ eloF) {
  __shared__ float lds[4][16][65];
  int lane = threadIdx.x & 63, w = threadIdx.x >> 6;
  int l15 = lane & 15, lg = lane >> 4;
  int rowblk0 = blockIdx.x * 2;            // 32 rows per block
  f32x4 acc[2][4] = {};
  for (int kb = 0; kb < DIN / 32; kb++) {
    bf16x8 ah[2], al[2], bh[4], bl[4];
    #pragma unroll
    for (int fm = 0; fm < 2; fm++) {
      size_t o = (((size_t)(rowblk0 + fm) * (DIN / 32) + kb) * 64 + lane) * 8;
      ah[fm] = *reinterpret_cast<const bf16x8*>(XhF + o);
      al[fm] = *reinterpret_cast<const bf16x8*>(XlF + o);
    }
    #pragma unroll
    for (int fn = 0; fn < 4; fn++) {
      size_t o = (((size_t)(w * 4 + fn) * (DIN / 32) + kb) * 64 + lane) * 8;
      bh[fn] = *reinterpret_cast<const bf16x8*>(WhF + o);
      bl[fn] = *reinterpret_cast<const bf16x8*>(WlF + o);
    }
    #pragma unroll
    for (int fm = 0; fm < 2; fm++)
      #pragma unroll
      for (int fn = 0; fn < 4; fn++) {
        acc[fm][fn] = __builtin_amdgcn_mfma_f32_16x16x32_bf16(ah[fm], bh[fn], acc[fm][fn], 0, 0, 0);
        acc[fm][fn] = __builtin_amdgcn_mfma_f32_16x16x32_bf16(ah[fm], bl[fn], acc[fm][fn], 0, 0, 0);
        acc[fm][fn] = __builtin_amdgcn_mfma_f32_16x16x32_bf16(al[fm], bh[fn], acc[fm][fn], 0, 0, 0);
        acc[fm][fn] = __builtin_amdgcn_mfma_f32_16x16x32_bf16(al[fm], bl[fn], acc[fm][fn], 0, 0, 0);
      }
  }
  // C/D (col=l15,row=lg*4+r) -> fragment-major via LDS permute
  for (int fm = 0; fm < 2; fm++) {
    #pragma unroll
    for (int fn = 0; fn < 4; fn++)
      #pragma unroll
      for (int r = 0; r < 4; r++)
        lds[w][lg * 4 + r][fn * 16 + l15] = acc[fm][fn][r];
    __syncthreads();
    #pragma unroll
    for (int cb = 0; cb < 2; cb++) {
      const float* src = &lds[w][l15][cb * 32 + lg * 8];
      bf16x8 hv, lv;
      #pragma unroll
      for (int j = 0; j < 8; j++) {
        float v = src[j];
        unsigned short h = f2bf(v);
        hv[j] = (short)h;
        lv[j] = (short)f2bf(v - bf2f(h));
      }
      size_t off = (((size_t)(rowblk0 + fm) * (DEMB / 32) + w * 2 + cb) * 64 + lane) * 8;
      *reinterpret_cast<bf16x8*>(ehiF + off) = hv;
      *reinterpret_cast<bf16x8*>(eloF + off) = lv;
    }
    __syncthreads();
  }
}

// ---------- 2) similarity (split-bf16, direct frag-major L2 loads) -> Apk both triangles ----------
__global__ __launch_bounds__(256) void sim_kernel(
    const unsigned short* __restrict__ ehiF, const unsigned short* __restrict__ eloF,
    unsigned int* __restrict__ Apk) {
  int bx = blockIdx.x, by = blockIdx.y;
  if (bx < by) return;                       // A symmetric: this block writes both triangles
  __shared__ unsigned short LTn[128][8];     // normal bit-rows (ushort per 16 cols)
  __shared__ unsigned short LTt[128][8];     // transposed
  int lane = threadIdx.x & 63;
  int w = threadIdx.x >> 6, wm = w >> 1, wn = w & 1;
  int l15 = lane & 15, lg = lane >> 4;
  int arb = by * 8 + wm * 4, brb = bx * 8 + wn * 4;

  f32x4 acc[4][4] = {};
  for (int kb = 0; kb < DEMB / 32; kb++) {
    bf16x8 bh[4], bl[4];
    #pragma unroll
    for (int fn = 0; fn < 4; fn++) {
      size_t o = (((size_t)(brb + fn) * (DEMB / 32) + kb) * 64 + lane) * 8;
      bh[fn] = *reinterpret_cast<const bf16x8*>(ehiF + o);
      bl[fn] = *reinterpret_cast<const bf16x8*>(eloF + o);
    }
    #pragma unroll
    for (int fm = 0; fm < 4; fm++) {
      size_t o = (((size_t)(arb + fm) * (DEMB / 32) + kb) * 64 + lane) * 8;
      bf16x8 ah = *reinterpret_cast<const bf16x8*>(ehiF + o);
      bf16x8 al = *reinterpret_cast<const bf16x8*>(eloF + o);
      #pragma unroll
      for (int fn = 0; fn < 4; fn++) {
        acc[fm][fn] = __builtin_amdgcn_mfma_f32_16x16x32_bf16(ah, bh[fn], acc[fm][fn], 0, 0, 0);
        acc[fm][fn] = __builtin_amdgcn_mfma_f32_16x16x32_bf16(ah, bl[fn], acc[fm][fn], 0, 0, 0);
        acc[fm][fn] = __builtin_amdgcn_mfma_f32_16x16x32_bf16(al, bh[fn], acc[fm][fn], 0, 0, 0);
      }
    }
  }
  // threshold + ballot; build normal and transposed bit-rows in LDS
  #pragma unroll
  for (int fm = 0; fm < 4; fm++)
    #pragma unroll
    for (int fn = 0; fn < 4; fn++) {
      unsigned long long bal[4];
      #pragma unroll
      for (int r = 0; r < 4; r++) {
        bal[r] = __ballot(acc[fm][fn][r] > 0.5f);
        if (l15 == 0)
          LTn[wm * 64 + fm * 16 + lg * 4 + r][wn * 4 + fn] =
              (unsigned short)(bal[r] >> (lg * 16));
      }
      unsigned int tv = 0;
      #pragma unroll
      for (int p = 0; p < 16; p++) {
        unsigned int half = (unsigned int)(bal[p & 3] >> ((p >> 2) * 16));
        tv |= ((half >> l15) & 1u) << p;
      }
      if (lg == 0) LTt[wn * 64 + fn * 16 + l15][wm * 4 + fm] = (unsigned short)tv;
    }
  __syncthreads();
  // assemble Apk dwords: dword(rowblk,S4,lane={row&15,lg}) byte t = bits k=S4*128+t*32+lg*8
  #pragma unroll
  for (int pass = 0; pass < 2; pass++) {
    int idx = pass * 256 + threadIdx.x;      // 0..511
    int rb4 = idx >> 6, ln = idx & 63;
    int lr = rb4 * 16 + (ln & 15), Lg = ln >> 4;
    unsigned int d = 0, d2 = 0;
    #pragma unroll
    for (int t = 0; t < 4; t++) {
      int bix = t * 4 + Lg;
      unsigned int u = LTn[lr][bix >> 1];
      d |= ((u >> ((bix & 1) * 8)) & 0xffu) << (t * 8);
      unsigned int u2 = LTt[lr][bix >> 1];
      d2 |= ((u2 >> ((bix & 1) * 8)) & 0xffu) << (t * 8);
    }
    Apk[((size_t)(by * 8 + rb4) * 64 + bx) * 64 + ln] = d;
    Apk[((size_t)(bx * 8 + rb4) * 64 + by) * 64 + ln] = d2;
  }
}

// ---------- 3) rdeg = 1/popcount, straight from Apk (coalesced) ----------
__global__ __launch_bounds__(256) void degree_kernel(
    const unsigned int* __restrict__ Apk, float* __restrict__ rdeg) {
  __shared__ int dg[4][16];
  int rowblk = blockIdx.x;
  int w = threadIdx.x >> 6, lane = threadIdx.x & 63;
  const unsigned int* base = Apk + (size_t)rowblk * 4096;
  int cnt = 0;
  #pragma unroll
  for (int s = 0; s < 16; s++) cnt += __popc(base[(w * 16 + s) * 64 + lane]);
  cnt += __shfl_xor(cnt, 16);
  cnt += __shfl_xor(cnt, 32);
  if (lane < 16) dg[w][lane] = cnt;
  __syncthreads();
  if (threadIdx.x < 16) {
    int c = dg[0][threadIdx.x] + dg[1][threadIdx.x] + dg[2][threadIdx.x] + dg[3][threadIdx.x];
    rdeg[rowblk * 16 + threadIdx.x] = (c == 0) ? 1.f : 1.f / (float)c;
  }
}

// ---------- 4) label init: support one-hot, query zero ----------
__global__ __launch_bounds__(256) void init_labels(
    const int* __restrict__ slab, float* __restrict__ labels,
    unsigned short* __restrict__ LtF) {
  int idx = blockIdx.x * 256 + threadIdx.x;
  int i = idx >> 6, c = idx & 63;
  float v = 0.f;
  if (i < NSUP && slab[i] == c) v = 1.f;
  labels[idx] = v;
  LtF[lfrag(i, c)] = f2bf(v);
}

// ---------- 5) fused prop: labels' = 0.5*labels + 0.5*(A@L)/deg ----------
// 512 blocks x 512 thr (8 waves): wave wk owns 16 rows x 64 cols x K-chunk 1024
__global__ __launch_bounds__(512) void prop_kernel(
    const unsigned int* __restrict__ Apk, const unsigned short* __restrict__ LtinF,
    const float* __restrict__ rdeg, float* __restrict__ labels,
    unsigned short* __restrict__ LtoutF, float* __restrict__ outq, int last) {
  __shared__ float red[8][16][67];
  int lane = threadIdx.x & 63;
  int wk = threadIdx.x >> 6;
  int l15 = lane & 15, lg = lane >> 4;
  int rowblk = blockIdx.x;
  const unsigned int* ap = Apk + ((size_t)rowblk * 64 + wk * 8) * 64 + lane;
  f32x4 acc[4] = {};
  #pragma unroll 2
  for (int s4 = 0; s4 < 8; s4++) {
    unsigned int d = ap[s4 * 64];
    #pragma unroll
    for (int t = 0; t < 4; t++) {
      unsigned int bb = (d >> (8 * t)) & 0xffu;
      u32x4 uu;
      uu.x = ((bb & 1u)   ? 0x3F80u : 0u) | ((bb & 2u)   ? 0x3F800000u : 0u);
      uu.y = ((bb & 4u)   ? 0x3F80u : 0u) | ((bb & 8u)   ? 0x3F800000u : 0u);
      uu.z = ((bb & 16u)  ? 0x3F80u : 0u) | ((bb & 32u)  ? 0x3F800000u : 0u);
      uu.w = ((bb & 64u)  ? 0x3F80u : 0u) | ((bb & 128u) ? 0x3F800000u : 0u);
      bf16x8 a = __builtin_bit_cast(bf16x8, uu);
      int kstep = (wk * 8 + s4) * 4 + t;
      #pragma unroll
      for (int fn = 0; fn < 4; fn++) {
        bf16x8 b = *reinterpret_cast<const bf16x8*>(
            LtinF + (((size_t)kstep * 4 + fn) * 64 + lane) * 8);
        acc[fn] = __builtin_amdgcn_mfma_f32_16x16x32_bf16(a, b, acc[fn], 0, 0, 0);
      }
    }
  }
  #pragma unroll
  for (int fn = 0; fn < 4; fn++)
    #pragma unroll
    for (int r = 0; r < 4; r++)
      red[wk][lg * 4 + r][fn * 16 + l15] = acc[fn][r];
  __syncthreads();
  for (int e = threadIdx.x; e < 16 * 64; e += 512) {
    int il = e >> 6, c = e & 63;
    float s = 0.f;
    #pragma unroll
    for (int p = 0; p < 8; p++) s += red[p][il][c];
    int i = rowblk * 16 + il;
    size_t idx = (size_t)i * NCLS + c;
    float v = 0.5f * labels[idx] + 0.5f * (s * rdeg[i]);
    labels[idx] = v;
    LtoutF[lfrag(i, c)] = f2bf(v);
    if (last && i >= NSUP) outq[idx - (size_t)NSUP * NCLS] = v;
  }
}

extern "C" void kernel_launch(void* const* d_in, const int* in_sizes, int n_in,
                              void* d_out, int out_size, void* d_ws, size_t ws_size,
                              hipStream_t stream) {
  const float* support = (const float*)d_in[0];
  const float* query   = (const float*)d_in[1];
  const float* W       = (const float*)d_in[2];
  const int*   slab    = (const int*)d_in[3];
  float* out = (float*)d_out;
  char* ws = (char*)d_ws;
  const size_t MB = (size_t)1 << 20;
  // Apk (written by sim, after emb_mfma is done) aliases XhF's region.
  unsigned short* XhF    = (unsigned short*)(ws);            // 8 MB (dead after emb_mfma)
  unsigned int*   Apk    = (unsigned int*)(ws);              // 8 MB (alias)
  unsigned short* XlF    = (unsigned short*)(ws + 8 * MB);   // 8 MB
  unsigned short* ehiF   = (unsigned short*)(ws + 16 * MB);  // 4 MB
  unsigned short* eloF   = (unsigned short*)(ws + 20 * MB);  // 4 MB
  unsigned short* WhF    = (unsigned short*)(ws + 24 * MB);  // 256 KB
  unsigned short* WlF    = (unsigned short*)(ws + 24 * MB + 256 * 1024); // 256 KB
  float*          labels = (float*)(ws + 25 * MB);           // 2 MB fp32 [8192][64]
  unsigned short* Lt0    = (unsigned short*)(ws + 27 * MB);  // 1 MB frag-major
  unsigned short* Lt1    = (unsigned short*)(ws + 28 * MB);  // 1 MB
  float*          rdeg   = (float*)(ws + 29 * MB);           // 32 KB

  splitX<<<NTOT / 4, 256, 0, stream>>>(support, query, XhF, XlF);
  splitW<<<DIN * DEMB / 8 / 256, 256, 0, stream>>>(W, WhF, WlF);
  emb_mfma<<<NTOT / 32, 256, 0, stream>>>(XhF, XlF, WhF, WlF, ehiF, eloF);
  sim_kernel<<<dim3(64, 64), 256, 0, stream>>>(ehiF, eloF, Apk);
  degree_kernel<<<NTOT / 16, 256, 0, stream>>>(Apk, rdeg);
  init_labels<<<NTOT * NCLS / 256, 256, 0, stream>>>(slab, labels, Lt0);
  for (int t = 0; t < 10; t++) {
    unsigned short* Li = (t & 1) ? Lt1 : Lt0;
    unsigned short* Lo = (t & 1) ? Lt0 : Lt1;
    prop_kernel<<<NTOT / 16, 512, 0, stream>>>(Apk, Li, rdeg, labels, Lo, out, (t == 9) ? 1 : 0);
  }
}